// Round 1
// baseline (422.279 us; speedup 1.0000x reference)
//
#include <hip/hip_runtime.h>

#define VINT 50000
#define NN   10000
#define KK   16
#define DINT 8
#define DEXT 16
#define DD   128
#define BB   2048

// ---------------------------------------------------------------------------
// Kernel 1: WE[v] = W @ E[v], ME[v] = M @ E[v]  for all v in [0, VINT)
// Grid: ceil(VINT/8) blocks x 128 threads. 8 E-rows staged in LDS per block;
// thread i computes output element i for all 8 rows (W/M row read amortized 8x).
// ---------------------------------------------------------------------------
__global__ __launch_bounds__(128) void k_precompute(
    const float* __restrict__ E, const float* __restrict__ W,
    const float* __restrict__ M, float* __restrict__ WE, float* __restrict__ ME)
{
    __shared__ float eld[8][DD];
    const int v0 = blockIdx.x * 8;
    const int t  = threadIdx.x;
    #pragma unroll
    for (int v = 0; v < 8; ++v) {
        int vv = v0 + v;
        eld[v][t] = (vv < VINT) ? E[vv * DD + t] : 0.f;
    }
    __syncthreads();

    float aW[8] = {0.f,0.f,0.f,0.f,0.f,0.f,0.f,0.f};
    float aM[8] = {0.f,0.f,0.f,0.f,0.f,0.f,0.f,0.f};
    const float* wr = W + t * DD;
    const float* mr = M + t * DD;
    for (int j = 0; j < DD; ++j) {
        float w = wr[j], m = mr[j];
        #pragma unroll
        for (int v = 0; v < 8; ++v) {
            aW[v] = fmaf(w, eld[v][j], aW[v]);
            aM[v] = fmaf(m, eld[v][j], aM[v]);
        }
    }
    #pragma unroll
    for (int v = 0; v < 8; ++v) {
        int vv = v0 + v;
        if (vv < VINT) {
            WE[vv * DD + t] = aW[v];
            ME[vv * DD + t] = aM[v];
        }
    }
}

// ---------------------------------------------------------------------------
// Kernel 2: per node n:
//   r[d] = sum_k relu( WE[node_ids[n,k]][d] + sum_e ME[neigh_ids[n,k,e]][d] )
//   h[n] = softmax(r)
// Grid: NN blocks x 128 threads (thread d owns column d).
// ---------------------------------------------------------------------------
__global__ __launch_bounds__(128) void k_node(
    const int* __restrict__ node_ids, const int* __restrict__ neigh_ids,
    const float* __restrict__ WE, const float* __restrict__ ME,
    float* __restrict__ H)
{
    const int n = blockIdx.x;
    const int d = threadIdx.x;
    const int* nid = node_ids + n * KK;
    const int* gid = neigh_ids + n * KK * DINT;

    float r = 0.f;
    for (int k = 0; k < KK; ++k) {
        float s = WE[nid[k] * DD + d];
        #pragma unroll
        for (int e = 0; e < DINT; ++e)
            s += ME[gid[k * DINT + e] * DD + d];
        r += fmaxf(s, 0.f);
    }

    // block softmax over 128 threads (2 waves)
    __shared__ float red[4];
    float m = r;
    #pragma unroll
    for (int off = 32; off >= 1; off >>= 1) m = fmaxf(m, __shfl_xor(m, off));
    if ((d & 63) == 0) red[d >> 6] = m;
    __syncthreads();
    m = fmaxf(red[0], red[1]);
    float ex = expf(r - m);
    float s2 = ex;
    #pragma unroll
    for (int off = 32; off >= 1; off >>= 1) s2 += __shfl_xor(s2, off);
    if ((d & 63) == 0) red[2 + (d >> 6)] = s2;
    __syncthreads();
    float tot = red[2] + red[3];
    H[n * DD + d] = ex / tot;
}

// ---------------------------------------------------------------------------
// Kernel 3: per node n:
//   ext_sum = sum_j h[ext_neigh[n,j]]
//   e_all[n] = softmax( relu( U @ h[n] + V @ ext_sum ) )
// Grid: NN blocks x 128 threads.
// ---------------------------------------------------------------------------
__global__ __launch_bounds__(128) void k_ext(
    const int* __restrict__ ext_neigh, const float* __restrict__ H,
    const float* __restrict__ U, const float* __restrict__ V,
    float* __restrict__ EALL)
{
    const int n = blockIdx.x;
    const int i = threadIdx.x;
    __shared__ float hl[DD], xl[DD];

    hl[i] = H[n * DD + i];
    const int* en = ext_neigh + n * DEXT;
    float es = 0.f;
    #pragma unroll
    for (int j = 0; j < DEXT; ++j) es += H[en[j] * DD + i];
    xl[i] = es;
    __syncthreads();

    float acc = 0.f;
    const float* ur = U + i * DD;
    const float* vr = V + i * DD;
    for (int j = 0; j < DD; ++j)
        acc = fmaf(ur[j], hl[j], fmaf(vr[j], xl[j], acc));
    acc = fmaxf(acc, 0.f);

    // block softmax over 128 threads
    __shared__ float red[4];
    float m = acc;
    #pragma unroll
    for (int off = 32; off >= 1; off >>= 1) m = fmaxf(m, __shfl_xor(m, off));
    if ((i & 63) == 0) red[i >> 6] = m;
    __syncthreads();
    m = fmaxf(red[0], red[1]);
    float ex = expf(acc - m);
    float s2 = ex;
    #pragma unroll
    for (int off = 32; off >= 1; off >>= 1) s2 += __shfl_xor(s2, off);
    if ((i & 63) == 0) red[2 + (i >> 6)] = s2;
    __syncthreads();
    float tot = red[2] + red[3];
    EALL[n * DD + i] = ex / tot;
}

// ---------------------------------------------------------------------------
// Kernel 4: per batch pair b:
//   x = leaky_relu(W1 @ [e_all[a]; e_all[bb]] + b1, 0.01)
//   out[b] = softmax(W2 @ x + b2)
// Grid: BB blocks x 128 threads.
// ---------------------------------------------------------------------------
__global__ __launch_bounds__(128) void k_mlp(
    const int* __restrict__ batch, const float* __restrict__ EALL,
    const float* __restrict__ W1, const float* __restrict__ b1,
    const float* __restrict__ W2, const float* __restrict__ b2,
    float* __restrict__ out)
{
    const int b = blockIdx.x;
    const int t = threadIdx.x;
    __shared__ float cat[2 * DD];
    const int ia = batch[2 * b];
    const int ib = batch[2 * b + 1];
    cat[t]      = EALL[ia * DD + t];
    cat[DD + t] = EALL[ib * DD + t];
    __syncthreads();

    float x = b1[t];
    const float* w1r = W1 + t * (2 * DD);
    for (int j = 0; j < 2 * DD; ++j) x = fmaf(w1r[j], cat[j], x);
    x = (x > 0.f) ? x : 0.01f * x;

    float p0 = W2[t] * x;        // W2[0, t]
    float p1 = W2[DD + t] * x;   // W2[1, t]
    __shared__ float red[4];
    #pragma unroll
    for (int off = 32; off >= 1; off >>= 1) {
        p0 += __shfl_xor(p0, off);
        p1 += __shfl_xor(p1, off);
    }
    if ((t & 63) == 0) { red[t >> 6] = p0; red[2 + (t >> 6)] = p1; }
    __syncthreads();
    if (t == 0) {
        float l0 = red[0] + red[1] + b2[0];
        float l1 = red[2] + red[3] + b2[1];
        float mm = fmaxf(l0, l1);
        float e0 = expf(l0 - mm), e1 = expf(l1 - mm);
        float inv = 1.f / (e0 + e1);
        out[2 * b]     = e0 * inv;
        out[2 * b + 1] = e1 * inv;
    }
}

// ---------------------------------------------------------------------------
extern "C" void kernel_launch(void* const* d_in, const int* in_sizes, int n_in,
                              void* d_out, int out_size, void* d_ws, size_t ws_size,
                              hipStream_t stream) {
    const int*   batch     = (const int*)d_in[0];
    const int*   node_ids  = (const int*)d_in[1];
    const int*   neigh_ids = (const int*)d_in[2];
    const int*   ext_neigh = (const int*)d_in[3];
    const float* E         = (const float*)d_in[4];
    const float* W         = (const float*)d_in[5];
    const float* M         = (const float*)d_in[6];
    const float* U         = (const float*)d_in[7];
    const float* V         = (const float*)d_in[8];
    const float* W1        = (const float*)d_in[9];
    const float* b1        = (const float*)d_in[10];
    const float* W2        = (const float*)d_in[11];
    const float* b2        = (const float*)d_in[12];

    float* ws = (float*)d_ws;
    float* WE = ws;                   // VINT*DD
    float* ME = WE + (size_t)VINT * DD; // VINT*DD
    float* H  = ME + (size_t)VINT * DD; // NN*DD
    float* EA = H  + (size_t)NN * DD;   // NN*DD
    float* out = (float*)d_out;

    k_precompute<<<(VINT + 7) / 8, 128, 0, stream>>>(E, W, M, WE, ME);
    k_node<<<NN, 128, 0, stream>>>(node_ids, neigh_ids, WE, ME, H);
    k_ext<<<NN, 128, 0, stream>>>(ext_neigh, H, U, V, EA);
    k_mlp<<<BB, 128, 0, stream>>>(batch, EA, W1, b1, W2, b2, out);
}

// Round 2
// 261.438 us; speedup vs baseline: 1.6152x; 1.6152x over previous
//
#include <hip/hip_runtime.h>

#define VINT 50000
#define NN   10000
#define KK   16
#define DINT 8
#define DEXT 16
#define DD   128
#define BB   2048

// ---------------------------------------------------------------------------
// Kernel 1: WE[v] = W @ E[v], ME[v] = M @ E[v].
// Register-tiled: block = 128 threads, 32 E-rows. Thread (rg,cq) owns
// rows rg*8..rg*8+7 x cols 4cq..4cq+3 for both matrices.
// W/M staged transposed in LDS per 32-wide j-tile: wlT[jj][i] = W[i][j0+jj],
// row stride 132 floats (16B-aligned, conflict-free b128 reads over i).
// ---------------------------------------------------------------------------
#define PROWS 32
__global__ __launch_bounds__(128) void k_precompute(
    const float* __restrict__ E, const float* __restrict__ W,
    const float* __restrict__ M, float* __restrict__ WE, float* __restrict__ ME)
{
    __shared__ float eld[PROWS][DD];      // 16 KB
    __shared__ float wlT[32 * 132];       // 16.9 KB
    __shared__ float mlT[32 * 132];       // 16.9 KB
    const int v0 = blockIdx.x * PROWS;
    const int t  = threadIdx.x;
    const int rg = t >> 5;    // row group 0..3 (rows rg*8..rg*8+7)
    const int cq = t & 31;    // col quad (cols 4cq..4cq+3)

    for (int r = 0; r < PROWS; ++r) {
        int vv = v0 + r;
        eld[r][t] = (vv < VINT) ? E[(size_t)vv * DD + t] : 0.f;
    }

    float4 aW[8], aM[8];
    #pragma unroll
    for (int r = 0; r < 8; ++r) {
        aW[r] = make_float4(0.f, 0.f, 0.f, 0.f);
        aM[r] = make_float4(0.f, 0.f, 0.f, 0.f);
    }

    for (int j0 = 0; j0 < DD; j0 += 32) {
        __syncthreads();   // covers eld on first iter; protects tile reuse after
        for (int x = t; x < DD * 32; x += 128) {
            int i = x >> 5, jj = x & 31;
            wlT[jj * 132 + i] = W[i * DD + j0 + jj];
            mlT[jj * 132 + i] = M[i * DD + j0 + jj];
        }
        __syncthreads();
        for (int jj = 0; jj < 32; jj += 4) {
            float4 e4[8];
            #pragma unroll
            for (int rr = 0; rr < 8; ++rr)
                e4[rr] = *(const float4*)&eld[rg * 8 + rr][j0 + jj];
            #pragma unroll
            for (int s = 0; s < 4; ++s) {
                float4 w4 = *(const float4*)&wlT[(jj + s) * 132 + 4 * cq];
                float4 m4 = *(const float4*)&mlT[(jj + s) * 132 + 4 * cq];
                #pragma unroll
                for (int rr = 0; rr < 8; ++rr) {
                    float e = (s == 0) ? e4[rr].x : (s == 1) ? e4[rr].y
                            : (s == 2) ? e4[rr].z : e4[rr].w;
                    aW[rr].x = fmaf(w4.x, e, aW[rr].x);
                    aW[rr].y = fmaf(w4.y, e, aW[rr].y);
                    aW[rr].z = fmaf(w4.z, e, aW[rr].z);
                    aW[rr].w = fmaf(w4.w, e, aW[rr].w);
                    aM[rr].x = fmaf(m4.x, e, aM[rr].x);
                    aM[rr].y = fmaf(m4.y, e, aM[rr].y);
                    aM[rr].z = fmaf(m4.z, e, aM[rr].z);
                    aM[rr].w = fmaf(m4.w, e, aM[rr].w);
                }
            }
        }
    }

    #pragma unroll
    for (int rr = 0; rr < 8; ++rr) {
        int vv = v0 + rg * 8 + rr;
        if (vv < VINT) {
            *(float4*)&WE[(size_t)vv * DD + 4 * cq] = aW[rr];
            *(float4*)&ME[(size_t)vv * DD + 4 * cq] = aM[rr];
        }
    }
}

// ---------------------------------------------------------------------------
// Kernel 2: per node n: r[d] = sum_k relu(WE[nid]+sum_e ME[gid]); h = softmax(r)
// 4 nodes per block; 32 lanes x float4 per node; wave-local softmax.
// ---------------------------------------------------------------------------
__global__ __launch_bounds__(128) void k_node(
    const int* __restrict__ node_ids, const int* __restrict__ neigh_ids,
    const float* __restrict__ WE, const float* __restrict__ ME,
    float* __restrict__ H)
{
    const int t = threadIdx.x;
    const int g = t >> 5, c = t & 31;
    const int n = blockIdx.x * 4 + g;
    const int* nid = node_ids + n * KK;
    const int* gid = neigh_ids + n * KK * DINT;

    float rx = 0.f, ry = 0.f, rz = 0.f, rw = 0.f;
    #pragma unroll 4
    for (int k = 0; k < KK; ++k) {
        float4 wv = *(const float4*)(WE + (size_t)nid[k] * DD + 4 * c);
        float sx = wv.x, sy = wv.y, sz = wv.z, sw = wv.w;
        #pragma unroll
        for (int e = 0; e < DINT; ++e) {
            float4 mv = *(const float4*)(ME + (size_t)gid[k * DINT + e] * DD + 4 * c);
            sx += mv.x; sy += mv.y; sz += mv.z; sw += mv.w;
        }
        rx += fmaxf(sx, 0.f); ry += fmaxf(sy, 0.f);
        rz += fmaxf(sz, 0.f); rw += fmaxf(sw, 0.f);
    }

    float mx = fmaxf(fmaxf(rx, ry), fmaxf(rz, rw));
    #pragma unroll
    for (int off = 16; off >= 1; off >>= 1) mx = fmaxf(mx, __shfl_xor(mx, off));
    float ex = expf(rx - mx), ey = expf(ry - mx), ez = expf(rz - mx), ew = expf(rw - mx);
    float s = ex + ey + ez + ew;
    #pragma unroll
    for (int off = 16; off >= 1; off >>= 1) s += __shfl_xor(s, off);
    float inv = 1.f / s;
    float4 o = make_float4(ex * inv, ey * inv, ez * inv, ew * inv);
    *(float4*)(H + (size_t)n * DD + 4 * c) = o;
}

// ---------------------------------------------------------------------------
// Kernel 3: per node n: e_all[n] = softmax(relu(U h[n] + V sum_j h[ext[n,j]]))
// 8 nodes per block; U/V staged transposed per j-tile (pad-129 scalar reads).
// ---------------------------------------------------------------------------
#define GEXT 8
__global__ __launch_bounds__(128) void k_ext(
    const int* __restrict__ ext_neigh, const float* __restrict__ H,
    const float* __restrict__ U, const float* __restrict__ V,
    float* __restrict__ EALL)
{
    __shared__ float hl[GEXT][DD];        // 4 KB
    __shared__ float xl[GEXT][DD];        // 4 KB
    __shared__ float ulT[32 * 129];       // 16.5 KB
    __shared__ float vlT[32 * 129];       // 16.5 KB
    __shared__ float sl[GEXT][DD + 1];    // 4.1 KB
    __shared__ float redm[GEXT], reds[GEXT];

    const int n0 = blockIdx.x * GEXT;
    const int t  = threadIdx.x;
    const int q  = t >> 5, c = t & 31;

    // gather h and ext_sum rows (float4, 32 lanes per row, 2 nodes per quarter)
    for (int gg = 0; gg < GEXT; gg += 4) {
        int gi = gg + q;
        int n  = n0 + gi;
        float4 hv = *(const float4*)(H + (size_t)n * DD + 4 * c);
        *(float4*)&hl[gi][4 * c] = hv;
        const int* en = ext_neigh + n * DEXT;
        float esx = 0.f, esy = 0.f, esz = 0.f, esw = 0.f;
        #pragma unroll
        for (int j = 0; j < DEXT; ++j) {
            float4 e4 = *(const float4*)(H + (size_t)en[j] * DD + 4 * c);
            esx += e4.x; esy += e4.y; esz += e4.z; esw += e4.w;
        }
        *(float4*)&xl[gi][4 * c] = make_float4(esx, esy, esz, esw);
    }

    float acc[GEXT];
    #pragma unroll
    for (int g = 0; g < GEXT; ++g) acc[g] = 0.f;

    for (int j0 = 0; j0 < DD; j0 += 32) {
        __syncthreads();   // covers hl/xl on first iter; tile reuse after
        for (int x = t; x < DD * 32; x += 128) {
            int i = x >> 5, jj = x & 31;
            ulT[jj * 129 + i] = U[i * DD + j0 + jj];
            vlT[jj * 129 + i] = V[i * DD + j0 + jj];
        }
        __syncthreads();
        for (int jj = 0; jj < 32; jj += 4) {
            float u0 = ulT[(jj + 0) * 129 + t], u1 = ulT[(jj + 1) * 129 + t];
            float u2 = ulT[(jj + 2) * 129 + t], u3 = ulT[(jj + 3) * 129 + t];
            float v0 = vlT[(jj + 0) * 129 + t], v1 = vlT[(jj + 1) * 129 + t];
            float v2 = vlT[(jj + 2) * 129 + t], v3 = vlT[(jj + 3) * 129 + t];
            #pragma unroll
            for (int g = 0; g < GEXT; ++g) {
                float4 h4 = *(const float4*)&hl[g][j0 + jj];
                float4 x4 = *(const float4*)&xl[g][j0 + jj];
                float a = acc[g];
                a = fmaf(u0, h4.x, a); a = fmaf(u1, h4.y, a);
                a = fmaf(u2, h4.z, a); a = fmaf(u3, h4.w, a);
                a = fmaf(v0, x4.x, a); a = fmaf(v1, x4.y, a);
                a = fmaf(v2, x4.z, a); a = fmaf(v3, x4.w, a);
                acc[g] = a;
            }
        }
    }

    #pragma unroll
    for (int g = 0; g < GEXT; ++g) sl[g][t] = fmaxf(acc[g], 0.f);
    __syncthreads();

    {   // per-node softmax stats: 16 threads per node, 8 elems each
        int g2 = t >> 4, p = t & 15;
        float m = -1e30f;
        #pragma unroll
        for (int z = 0; z < 8; ++z) m = fmaxf(m, sl[g2][p * 8 + z]);
        #pragma unroll
        for (int off = 8; off >= 1; off >>= 1) m = fmaxf(m, __shfl_xor(m, off));
        float s = 0.f;
        #pragma unroll
        for (int z = 0; z < 8; ++z) s += expf(sl[g2][p * 8 + z] - m);
        #pragma unroll
        for (int off = 8; off >= 1; off >>= 1) s += __shfl_xor(s, off);
        if (p == 0) { redm[g2] = m; reds[g2] = s; }
    }
    __syncthreads();

    #pragma unroll
    for (int g = 0; g < GEXT; ++g) {
        float val = fmaxf(acc[g], 0.f);
        EALL[(size_t)(n0 + g) * DD + t] = expf(val - redm[g]) / reds[g];
    }
}

// ---------------------------------------------------------------------------
// Kernel 4: per batch pair: 2-layer MLP head + softmax(2)
// ---------------------------------------------------------------------------
__global__ __launch_bounds__(128) void k_mlp(
    const int* __restrict__ batch, const float* __restrict__ EALL,
    const float* __restrict__ W1, const float* __restrict__ b1,
    const float* __restrict__ W2, const float* __restrict__ b2,
    float* __restrict__ out)
{
    const int b = blockIdx.x;
    const int t = threadIdx.x;
    __shared__ float cat[2 * DD];
    const int ia = batch[2 * b];
    const int ib = batch[2 * b + 1];
    cat[t]      = EALL[(size_t)ia * DD + t];
    cat[DD + t] = EALL[(size_t)ib * DD + t];
    __syncthreads();

    float x = b1[t];
    const float* w1r = W1 + t * (2 * DD);
    for (int j = 0; j < 2 * DD; ++j) x = fmaf(w1r[j], cat[j], x);
    x = (x > 0.f) ? x : 0.01f * x;

    float p0 = W2[t] * x;
    float p1 = W2[DD + t] * x;
    __shared__ float red[4];
    #pragma unroll
    for (int off = 32; off >= 1; off >>= 1) {
        p0 += __shfl_xor(p0, off);
        p1 += __shfl_xor(p1, off);
    }
    if ((t & 63) == 0) { red[t >> 6] = p0; red[2 + (t >> 6)] = p1; }
    __syncthreads();
    if (t == 0) {
        float l0 = red[0] + red[1] + b2[0];
        float l1 = red[2] + red[3] + b2[1];
        float mm = fmaxf(l0, l1);
        float e0 = expf(l0 - mm), e1 = expf(l1 - mm);
        float inv = 1.f / (e0 + e1);
        out[2 * b]     = e0 * inv;
        out[2 * b + 1] = e1 * inv;
    }
}

// ---------------------------------------------------------------------------
extern "C" void kernel_launch(void* const* d_in, const int* in_sizes, int n_in,
                              void* d_out, int out_size, void* d_ws, size_t ws_size,
                              hipStream_t stream) {
    const int*   batch     = (const int*)d_in[0];
    const int*   node_ids  = (const int*)d_in[1];
    const int*   neigh_ids = (const int*)d_in[2];
    const int*   ext_neigh = (const int*)d_in[3];
    const float* E         = (const float*)d_in[4];
    const float* W         = (const float*)d_in[5];
    const float* M         = (const float*)d_in[6];
    const float* U         = (const float*)d_in[7];
    const float* V         = (const float*)d_in[8];
    const float* W1        = (const float*)d_in[9];
    const float* b1        = (const float*)d_in[10];
    const float* W2        = (const float*)d_in[11];
    const float* b2        = (const float*)d_in[12];

    float* ws = (float*)d_ws;
    float* WE = ws;                     // VINT*DD
    float* ME = WE + (size_t)VINT * DD; // VINT*DD
    float* H  = ME + (size_t)VINT * DD; // NN*DD
    float* EA = H  + (size_t)NN * DD;   // NN*DD
    float* out = (float*)d_out;

    k_precompute<<<(VINT + PROWS - 1) / PROWS, 128, 0, stream>>>(E, W, M, WE, ME);
    k_node<<<NN / 4, 128, 0, stream>>>(node_ids, neigh_ids, WE, ME, H);
    k_ext<<<NN / GEXT, 128, 0, stream>>>(ext_neigh, H, U, V, EA);
    k_mlp<<<BB, 128, 0, stream>>>(batch, EA, W1, b1, W2, b2, out);
}

// Round 3
// 241.915 us; speedup vs baseline: 1.7456x; 1.0807x over previous
//
#include <hip/hip_runtime.h>

#define VINT 50000
#define NN   10000
#define KK   16
#define DINT 8
#define DEXT 16
#define DD   128
#define BB   2048

// ---------------------------------------------------------------------------
// Kernel 1: WE[v] = W @ E[v], ME[v] = M @ E[v].
// j-outer register-tiled GEMM. Block = 128 threads, 32 E-rows.
// Per 16-wide j-tile: stage E subtile (32x16) + W^T/M^T subtile (16x128) in
// LDS (19 KB total -> 8 blocks/CU), then each thread (rg,cq) does
// 8 rows x 4 cols x 2 mats FMAs. Transpose staging is lane-consecutive in i
// (<=2-way bank aliasing = free). Accumulators live in VGPRs across tiles.
// ---------------------------------------------------------------------------
#define PROWS 32
#define JT 16
__global__ __launch_bounds__(128, 4) void k_precompute(
    const float* __restrict__ E, const float* __restrict__ W,
    const float* __restrict__ M, float* __restrict__ WE, float* __restrict__ ME)
{
    __shared__ float eld[PROWS][20];   // 2.5 KB (pad 20: rows 16B-aligned)
    __shared__ float wlT[JT][132];     // 8.25 KB
    __shared__ float mlT[JT][132];     // 8.25 KB
    const int v0 = blockIdx.x * PROWS;
    const int t  = threadIdx.x;
    const int rg = t >> 5;    // row group 0..3 (rows rg*8..rg*8+7)
    const int cq = t & 31;    // col quad (cols 4cq..4cq+3)
    const int il = t >> 2;    // 0..31 (staging: i-lane)
    const int jq = t & 3;     // 0..3  (staging: j-quad)

    float4 aW[8], aM[8];
    #pragma unroll
    for (int r = 0; r < 8; ++r) {
        aW[r] = make_float4(0.f, 0.f, 0.f, 0.f);
        aM[r] = make_float4(0.f, 0.f, 0.f, 0.f);
    }

    for (int j0 = 0; j0 < DD; j0 += JT) {
        __syncthreads();   // protect LDS reuse from previous tile's readers
        // --- stage E subtile: rows v0..v0+31, cols j0..j0+15 (1 float4/thread)
        {
            int vv = v0 + il;
            float4 ev = (vv < VINT) ? *(const float4*)&E[(size_t)vv * DD + j0 + 4 * jq]
                                    : make_float4(0.f, 0.f, 0.f, 0.f);
            eld[il][4 * jq + 0] = ev.x;
            eld[il][4 * jq + 1] = ev.y;
            eld[il][4 * jq + 2] = ev.z;
            eld[il][4 * jq + 3] = ev.w;
        }
        // --- stage W^T / M^T subtile: wlT[jj][i] = W[i][j0+jj]
        // writes are consecutive-i across lanes -> <=2-way bank aliasing
        #pragma unroll
        for (int rep = 0; rep < 8; ++rep) {
            int i = rep * 16 + il;                 // il 0..31 -> two reps overlap? no: il>>? 
            // il spans 0..31; use only il<16 lanes pattern would idle half.
            // Instead: i = rep*16 + (il & 15), second half of lanes does M.
            ;
        }
        {
            // lanes split: q2 = il>>4 (0 -> W, 1 -> M), ii = il&15
            int q2 = il >> 4, ii = il & 15;
            const float* S = q2 ? M : W;
            float* dst = q2 ? &mlT[0][0] : &wlT[0][0];
            #pragma unroll
            for (int rep = 0; rep < 8; ++rep) {
                int i = rep * 16 + ii;
                float4 sv = *(const float4*)&S[i * DD + j0 + 4 * jq];
                dst[(4 * jq + 0) * 132 + i] = sv.x;
                dst[(4 * jq + 1) * 132 + i] = sv.y;
                dst[(4 * jq + 2) * 132 + i] = sv.z;
                dst[(4 * jq + 3) * 132 + i] = sv.w;
            }
        }
        __syncthreads();
        // --- compute on the tile
        #pragma unroll
        for (int jj = 0; jj < JT; jj += 4) {
            float4 e4[8];
            #pragma unroll
            for (int rr = 0; rr < 8; ++rr)
                e4[rr] = *(const float4*)&eld[rg * 8 + rr][jj];
            #pragma unroll
            for (int s = 0; s < 4; ++s) {
                float4 w4 = *(const float4*)&wlT[jj + s][4 * cq];
                float4 m4 = *(const float4*)&mlT[jj + s][4 * cq];
                #pragma unroll
                for (int rr = 0; rr < 8; ++rr) {
                    float e = (s == 0) ? e4[rr].x : (s == 1) ? e4[rr].y
                            : (s == 2) ? e4[rr].z : e4[rr].w;
                    aW[rr].x = fmaf(w4.x, e, aW[rr].x);
                    aW[rr].y = fmaf(w4.y, e, aW[rr].y);
                    aW[rr].z = fmaf(w4.z, e, aW[rr].z);
                    aW[rr].w = fmaf(w4.w, e, aW[rr].w);
                    aM[rr].x = fmaf(m4.x, e, aM[rr].x);
                    aM[rr].y = fmaf(m4.y, e, aM[rr].y);
                    aM[rr].z = fmaf(m4.z, e, aM[rr].z);
                    aM[rr].w = fmaf(m4.w, e, aM[rr].w);
                }
            }
        }
    }

    #pragma unroll
    for (int rr = 0; rr < 8; ++rr) {
        int vv = v0 + rg * 8 + rr;
        if (vv < VINT) {
            *(float4*)&WE[(size_t)vv * DD + 4 * cq] = aW[rr];
            *(float4*)&ME[(size_t)vv * DD + 4 * cq] = aM[rr];
        }
    }
}

// ---------------------------------------------------------------------------
// Kernel 2: per node n: r[d] = sum_k relu(WE[nid]+sum_e ME[gid]); h = softmax(r)
// 4 nodes per block; 32 lanes x float4 per node; wave-local softmax.
// ---------------------------------------------------------------------------
__global__ __launch_bounds__(128) void k_node(
    const int* __restrict__ node_ids, const int* __restrict__ neigh_ids,
    const float* __restrict__ WE, const float* __restrict__ ME,
    float* __restrict__ H)
{
    const int t = threadIdx.x;
    const int g = t >> 5, c = t & 31;
    const int n = blockIdx.x * 4 + g;
    const int* nid = node_ids + n * KK;
    const int* gid = neigh_ids + n * KK * DINT;

    float rx = 0.f, ry = 0.f, rz = 0.f, rw = 0.f;
    #pragma unroll 4
    for (int k = 0; k < KK; ++k) {
        float4 wv = *(const float4*)(WE + (size_t)nid[k] * DD + 4 * c);
        float sx = wv.x, sy = wv.y, sz = wv.z, sw = wv.w;
        #pragma unroll
        for (int e = 0; e < DINT; ++e) {
            float4 mv = *(const float4*)(ME + (size_t)gid[k * DINT + e] * DD + 4 * c);
            sx += mv.x; sy += mv.y; sz += mv.z; sw += mv.w;
        }
        rx += fmaxf(sx, 0.f); ry += fmaxf(sy, 0.f);
        rz += fmaxf(sz, 0.f); rw += fmaxf(sw, 0.f);
    }

    float mx = fmaxf(fmaxf(rx, ry), fmaxf(rz, rw));
    #pragma unroll
    for (int off = 16; off >= 1; off >>= 1) mx = fmaxf(mx, __shfl_xor(mx, off));
    float ex = expf(rx - mx), ey = expf(ry - mx), ez = expf(rz - mx), ew = expf(rw - mx);
    float s = ex + ey + ez + ew;
    #pragma unroll
    for (int off = 16; off >= 1; off >>= 1) s += __shfl_xor(s, off);
    float inv = 1.f / s;
    float4 o = make_float4(ex * inv, ey * inv, ez * inv, ew * inv);
    *(float4*)(H + (size_t)n * DD + 4 * c) = o;
}

// ---------------------------------------------------------------------------
// Kernel 3: per node n: e_all[n] = softmax(relu(U h[n] + V sum_j h[ext[n,j]]))
// 8 nodes per block; U/V staged transposed per j-tile (pad-129 scalar reads).
// ---------------------------------------------------------------------------
#define GEXT 8
__global__ __launch_bounds__(128) void k_ext(
    const int* __restrict__ ext_neigh, const float* __restrict__ H,
    const float* __restrict__ U, const float* __restrict__ V,
    float* __restrict__ EALL)
{
    __shared__ float hl[GEXT][DD];        // 4 KB
    __shared__ float xl[GEXT][DD];        // 4 KB
    __shared__ float ulT[32 * 129];       // 16.5 KB
    __shared__ float vlT[32 * 129];       // 16.5 KB
    __shared__ float sl[GEXT][DD + 1];    // 4.1 KB
    __shared__ float redm[GEXT], reds[GEXT];

    const int n0 = blockIdx.x * GEXT;
    const int t  = threadIdx.x;
    const int q  = t >> 5, c = t & 31;

    for (int gg = 0; gg < GEXT; gg += 4) {
        int gi = gg + q;
        int n  = n0 + gi;
        float4 hv = *(const float4*)(H + (size_t)n * DD + 4 * c);
        *(float4*)&hl[gi][4 * c] = hv;
        const int* en = ext_neigh + n * DEXT;
        float esx = 0.f, esy = 0.f, esz = 0.f, esw = 0.f;
        #pragma unroll
        for (int j = 0; j < DEXT; ++j) {
            float4 e4 = *(const float4*)(H + (size_t)en[j] * DD + 4 * c);
            esx += e4.x; esy += e4.y; esz += e4.z; esw += e4.w;
        }
        *(float4*)&xl[gi][4 * c] = make_float4(esx, esy, esz, esw);
    }

    float acc[GEXT];
    #pragma unroll
    for (int g = 0; g < GEXT; ++g) acc[g] = 0.f;

    for (int j0 = 0; j0 < DD; j0 += 32) {
        __syncthreads();
        for (int x = t; x < DD * 32; x += 128) {
            int i = x >> 5, jj = x & 31;
            ulT[jj * 129 + i] = U[i * DD + j0 + jj];
            vlT[jj * 129 + i] = V[i * DD + j0 + jj];
        }
        __syncthreads();
        for (int jj = 0; jj < 32; jj += 4) {
            float u0 = ulT[(jj + 0) * 129 + t], u1 = ulT[(jj + 1) * 129 + t];
            float u2 = ulT[(jj + 2) * 129 + t], u3 = ulT[(jj + 3) * 129 + t];
            float v0 = vlT[(jj + 0) * 129 + t], v1 = vlT[(jj + 1) * 129 + t];
            float v2 = vlT[(jj + 2) * 129 + t], v3 = vlT[(jj + 3) * 129 + t];
            #pragma unroll
            for (int g = 0; g < GEXT; ++g) {
                float4 h4 = *(const float4*)&hl[g][j0 + jj];
                float4 x4 = *(const float4*)&xl[g][j0 + jj];
                float a = acc[g];
                a = fmaf(u0, h4.x, a); a = fmaf(u1, h4.y, a);
                a = fmaf(u2, h4.z, a); a = fmaf(u3, h4.w, a);
                a = fmaf(v0, x4.x, a); a = fmaf(v1, x4.y, a);
                a = fmaf(v2, x4.z, a); a = fmaf(v3, x4.w, a);
                acc[g] = a;
            }
        }
    }

    #pragma unroll
    for (int g = 0; g < GEXT; ++g) sl[g][t] = fmaxf(acc[g], 0.f);
    __syncthreads();

    {
        int g2 = t >> 4, p = t & 15;
        float m = -1e30f;
        #pragma unroll
        for (int z = 0; z < 8; ++z) m = fmaxf(m, sl[g2][p * 8 + z]);
        #pragma unroll
        for (int off = 8; off >= 1; off >>= 1) m = fmaxf(m, __shfl_xor(m, off));
        float s = 0.f;
        #pragma unroll
        for (int z = 0; z < 8; ++z) s += expf(sl[g2][p * 8 + z] - m);
        #pragma unroll
        for (int off = 8; off >= 1; off >>= 1) s += __shfl_xor(s, off);
        if (p == 0) { redm[g2] = m; reds[g2] = s; }
    }
    __syncthreads();

    #pragma unroll
    for (int g = 0; g < GEXT; ++g) {
        float val = fmaxf(acc[g], 0.f);
        EALL[(size_t)(n0 + g) * DD + t] = expf(val - redm[g]) / reds[g];
    }
}

// ---------------------------------------------------------------------------
// Kernel 4: per batch pair: 2-layer MLP head + softmax(2)
// ---------------------------------------------------------------------------
__global__ __launch_bounds__(128) void k_mlp(
    const int* __restrict__ batch, const float* __restrict__ EALL,
    const float* __restrict__ W1, const float* __restrict__ b1,
    const float* __restrict__ W2, const float* __restrict__ b2,
    float* __restrict__ out)
{
    const int b = blockIdx.x;
    const int t = threadIdx.x;
    __shared__ float cat[2 * DD];
    const int ia = batch[2 * b];
    const int ib = batch[2 * b + 1];
    cat[t]      = EALL[(size_t)ia * DD + t];
    cat[DD + t] = EALL[(size_t)ib * DD + t];
    __syncthreads();

    float x = b1[t];
    const float* w1r = W1 + t * (2 * DD);
    for (int j = 0; j < 2 * DD; ++j) x = fmaf(w1r[j], cat[j], x);
    x = (x > 0.f) ? x : 0.01f * x;

    float p0 = W2[t] * x;
    float p1 = W2[DD + t] * x;
    __shared__ float red[4];
    #pragma unroll
    for (int off = 32; off >= 1; off >>= 1) {
        p0 += __shfl_xor(p0, off);
        p1 += __shfl_xor(p1, off);
    }
    if ((t & 63) == 0) { red[t >> 6] = p0; red[2 + (t >> 6)] = p1; }
    __syncthreads();
    if (t == 0) {
        float l0 = red[0] + red[1] + b2[0];
        float l1 = red[2] + red[3] + b2[1];
        float mm = fmaxf(l0, l1);
        float e0 = expf(l0 - mm), e1 = expf(l1 - mm);
        float inv = 1.f / (e0 + e1);
        out[2 * b]     = e0 * inv;
        out[2 * b + 1] = e1 * inv;
    }
}

// ---------------------------------------------------------------------------
extern "C" void kernel_launch(void* const* d_in, const int* in_sizes, int n_in,
                              void* d_out, int out_size, void* d_ws, size_t ws_size,
                              hipStream_t stream) {
    const int*   batch     = (const int*)d_in[0];
    const int*   node_ids  = (const int*)d_in[1];
    const int*   neigh_ids = (const int*)d_in[2];
    const int*   ext_neigh = (const int*)d_in[3];
    const float* E         = (const float*)d_in[4];
    const float* W         = (const float*)d_in[5];
    const float* M         = (const float*)d_in[6];
    const float* U         = (const float*)d_in[7];
    const float* V         = (const float*)d_in[8];
    const float* W1        = (const float*)d_in[9];
    const float* b1        = (const float*)d_in[10];
    const float* W2        = (const float*)d_in[11];
    const float* b2        = (const float*)d_in[12];

    float* ws = (float*)d_ws;
    float* WE = ws;                     // VINT*DD
    float* ME = WE + (size_t)VINT * DD; // VINT*DD
    float* H  = ME + (size_t)VINT * DD; // NN*DD
    float* EA = H  + (size_t)NN * DD;   // NN*DD
    float* out = (float*)d_out;

    k_precompute<<<(VINT + PROWS - 1) / PROWS, 128, 0, stream>>>(E, W, M, WE, ME);
    k_node<<<NN / 4, 128, 0, stream>>>(node_ids, neigh_ids, WE, ME, H);
    k_ext<<<NN / GEXT, 128, 0, stream>>>(ext_neigh, H, U, V, EA);
    k_mlp<<<BB, 128, 0, stream>>>(batch, EA, W1, b1, W2, b2, out);
}

// Round 4
// 191.467 us; speedup vs baseline: 2.2055x; 1.2635x over previous
//
#include <hip/hip_runtime.h>
#include <hip/hip_fp16.h>

#define VINT 50000
#define NN   10000
#define KK   16
#define DINT 8
#define DEXT 16
#define DD   128
#define BB   2048
#define PROWS 32
#define JT 16

struct __align__(8) half4 { __half2 a, b; };

__device__ inline void store_quad(float* p, float4 v) { *(float4*)p = v; }
__device__ inline void store_quad(__half* p, float4 v) {
    half4 h;
    h.a = __floats2half2_rn(v.x, v.y);
    h.b = __floats2half2_rn(v.z, v.w);
    *(half4*)p = h;
}

// ---------------------------------------------------------------------------
// Generic dual-matrix row-transform: OA[v] = A @ X[v], OB[v] = B @ X[v].
// j-outer register-tiled; 19 KB LDS -> high occupancy. Used twice:
//   stage 1: X=E (VINT rows), A=W, B=M, OutT=__half
//   stage 3: X=H (NN rows),   A=U, B=V, OutT=float
// ---------------------------------------------------------------------------
template <typename OutT>
__global__ __launch_bounds__(128, 4) void k_gemm_dual(
    const float* __restrict__ X, const float* __restrict__ A,
    const float* __restrict__ B, OutT* __restrict__ OA, OutT* __restrict__ OB,
    int nrows)
{
    __shared__ float eld[PROWS][20];   // 2.5 KB
    __shared__ float wlT[JT][132];     // 8.25 KB
    __shared__ float mlT[JT][132];     // 8.25 KB
    const int v0 = blockIdx.x * PROWS;
    const int t  = threadIdx.x;
    const int rg = t >> 5;
    const int cq = t & 31;
    const int il = t >> 2;
    const int jq = t & 3;

    float4 aW[8], aM[8];
    #pragma unroll
    for (int r = 0; r < 8; ++r) {
        aW[r] = make_float4(0.f, 0.f, 0.f, 0.f);
        aM[r] = make_float4(0.f, 0.f, 0.f, 0.f);
    }

    for (int j0 = 0; j0 < DD; j0 += JT) {
        __syncthreads();
        {   // stage X subtile: rows v0..v0+31, cols j0..j0+15
            int vv = v0 + il;
            float4 ev = (vv < nrows) ? *(const float4*)&X[(size_t)vv * DD + j0 + 4 * jq]
                                     : make_float4(0.f, 0.f, 0.f, 0.f);
            eld[il][4 * jq + 0] = ev.x;
            eld[il][4 * jq + 1] = ev.y;
            eld[il][4 * jq + 2] = ev.z;
            eld[il][4 * jq + 3] = ev.w;
        }
        {   // stage A^T / B^T subtile: wlT[jj][i] = A[i][j0+jj]
            int q2 = il >> 4, ii = il & 15;
            const float* S = q2 ? B : A;
            float* dst = q2 ? &mlT[0][0] : &wlT[0][0];
            #pragma unroll
            for (int rep = 0; rep < 8; ++rep) {
                int i = rep * 16 + ii;
                float4 sv = *(const float4*)&S[i * DD + j0 + 4 * jq];
                dst[(4 * jq + 0) * 132 + i] = sv.x;
                dst[(4 * jq + 1) * 132 + i] = sv.y;
                dst[(4 * jq + 2) * 132 + i] = sv.z;
                dst[(4 * jq + 3) * 132 + i] = sv.w;
            }
        }
        __syncthreads();
        #pragma unroll
        for (int jj = 0; jj < JT; jj += 4) {
            float4 e4[8];
            #pragma unroll
            for (int rr = 0; rr < 8; ++rr)
                e4[rr] = *(const float4*)&eld[rg * 8 + rr][jj];
            #pragma unroll
            for (int s = 0; s < 4; ++s) {
                float4 w4 = *(const float4*)&wlT[jj + s][4 * cq];
                float4 m4 = *(const float4*)&mlT[jj + s][4 * cq];
                #pragma unroll
                for (int rr = 0; rr < 8; ++rr) {
                    float e = (s == 0) ? e4[rr].x : (s == 1) ? e4[rr].y
                            : (s == 2) ? e4[rr].z : e4[rr].w;
                    aW[rr].x = fmaf(w4.x, e, aW[rr].x);
                    aW[rr].y = fmaf(w4.y, e, aW[rr].y);
                    aW[rr].z = fmaf(w4.z, e, aW[rr].z);
                    aW[rr].w = fmaf(w4.w, e, aW[rr].w);
                    aM[rr].x = fmaf(m4.x, e, aM[rr].x);
                    aM[rr].y = fmaf(m4.y, e, aM[rr].y);
                    aM[rr].z = fmaf(m4.z, e, aM[rr].z);
                    aM[rr].w = fmaf(m4.w, e, aM[rr].w);
                }
            }
        }
    }

    #pragma unroll
    for (int rr = 0; rr < 8; ++rr) {
        int vv = v0 + rg * 8 + rr;
        if (vv < nrows) {
            store_quad(&OA[(size_t)vv * DD + 4 * cq], aW[rr]);
            store_quad(&OB[(size_t)vv * DD + 4 * cq], aM[rr]);
        }
    }
}

// ---------------------------------------------------------------------------
// Kernel 2: per node n: r[d] = sum_k relu(WE[nid]+sum_e ME[gid]); h = softmax(r)
// fp16 tables; 4 nodes/block, 32 lanes x half4 per node; indices staged in LDS
// so row-gathers have no index-load dependency; wave-local softmax.
// ---------------------------------------------------------------------------
__global__ __launch_bounds__(128) void k_node(
    const int* __restrict__ node_ids, const int* __restrict__ neigh_ids,
    const __half* __restrict__ WE, const __half* __restrict__ ME,
    float* __restrict__ H)
{
    __shared__ int idx[4][KK * (1 + DINT)];   // per node: [0..15]=nid, [16..143]=gid
    const int t  = threadIdx.x;
    const int n0 = blockIdx.x * 4;

    if (t < 4 * KK) idx[t >> 4][t & 15] = node_ids[n0 * KK + t];
    for (int x = t; x < 4 * KK * DINT; x += 128)
        idx[x >> 7][KK + (x & 127)] = neigh_ids[n0 * KK * DINT + x];
    __syncthreads();

    const int g = t >> 5, c = t & 31;
    const int n = n0 + g;
    const int* ids = idx[g];

    float rx = 0.f, ry = 0.f, rz = 0.f, rw = 0.f;
    #pragma unroll 4
    for (int k = 0; k < KK; ++k) {
        half4 wv = *(const half4*)(WE + (size_t)ids[k] * DD + 4 * c);
        float2 lo = __half22float2(wv.a), hi = __half22float2(wv.b);
        float sx = lo.x, sy = lo.y, sz = hi.x, sw = hi.y;
        #pragma unroll
        for (int e = 0; e < DINT; ++e) {
            half4 mv = *(const half4*)(ME + (size_t)ids[KK + k * DINT + e] * DD + 4 * c);
            float2 ml = __half22float2(mv.a), mh = __half22float2(mv.b);
            sx += ml.x; sy += ml.y; sz += mh.x; sw += mh.y;
        }
        rx += fmaxf(sx, 0.f); ry += fmaxf(sy, 0.f);
        rz += fmaxf(sz, 0.f); rw += fmaxf(sw, 0.f);
    }

    float mx = fmaxf(fmaxf(rx, ry), fmaxf(rz, rw));
    #pragma unroll
    for (int off = 16; off >= 1; off >>= 1) mx = fmaxf(mx, __shfl_xor(mx, off));
    float ex = expf(rx - mx), ey = expf(ry - mx), ez = expf(rz - mx), ew = expf(rw - mx);
    float s = ex + ey + ez + ew;
    #pragma unroll
    for (int off = 16; off >= 1; off >>= 1) s += __shfl_xor(s, off);
    float inv = 1.f / s;
    *(float4*)(H + (size_t)n * DD + 4 * c) = make_float4(ex * inv, ey * inv, ez * inv, ew * inv);
}

// ---------------------------------------------------------------------------
// Kernel 3b: per node n: e_all[n] = softmax(relu(UH[n] + sum_j VH[ext[n,j]]))
// (uses linearity: V @ sum_j h[e_j] = sum_j (V@h)[e_j]). Pure gather kernel.
// ---------------------------------------------------------------------------
__global__ __launch_bounds__(128) void k_ext2(
    const int* __restrict__ ext_neigh, const float* __restrict__ UH,
    const float* __restrict__ VH, float* __restrict__ EALL)
{
    __shared__ int idx[4][DEXT];
    const int t  = threadIdx.x;
    const int n0 = blockIdx.x * 4;
    if (t < 4 * DEXT) idx[t >> 4][t & 15] = ext_neigh[n0 * DEXT + t];
    __syncthreads();

    const int g = t >> 5, c = t & 31;
    const int n = n0 + g;
    float4 a = *(const float4*)(UH + (size_t)n * DD + 4 * c);
    float sx = a.x, sy = a.y, sz = a.z, sw = a.w;
    #pragma unroll
    for (int j = 0; j < DEXT; ++j) {
        float4 v = *(const float4*)(VH + (size_t)idx[g][j] * DD + 4 * c);
        sx += v.x; sy += v.y; sz += v.z; sw += v.w;
    }
    sx = fmaxf(sx, 0.f); sy = fmaxf(sy, 0.f);
    sz = fmaxf(sz, 0.f); sw = fmaxf(sw, 0.f);

    float mx = fmaxf(fmaxf(sx, sy), fmaxf(sz, sw));
    #pragma unroll
    for (int off = 16; off >= 1; off >>= 1) mx = fmaxf(mx, __shfl_xor(mx, off));
    float ex = expf(sx - mx), ey = expf(sy - mx), ez = expf(sz - mx), ew = expf(sw - mx);
    float s = ex + ey + ez + ew;
    #pragma unroll
    for (int off = 16; off >= 1; off >>= 1) s += __shfl_xor(s, off);
    float inv = 1.f / s;
    *(float4*)(EALL + (size_t)n * DD + 4 * c) = make_float4(ex * inv, ey * inv, ez * inv, ew * inv);
}

// ---------------------------------------------------------------------------
// Kernel 4: per batch pair: 2-layer MLP head + softmax(2)
// ---------------------------------------------------------------------------
__global__ __launch_bounds__(128) void k_mlp(
    const int* __restrict__ batch, const float* __restrict__ EALL,
    const float* __restrict__ W1, const float* __restrict__ b1,
    const float* __restrict__ W2, const float* __restrict__ b2,
    float* __restrict__ out)
{
    const int b = blockIdx.x;
    const int t = threadIdx.x;
    __shared__ float cat[2 * DD];
    const int ia = batch[2 * b];
    const int ib = batch[2 * b + 1];
    cat[t]      = EALL[(size_t)ia * DD + t];
    cat[DD + t] = EALL[(size_t)ib * DD + t];
    __syncthreads();

    float x = b1[t];
    const float* w1r = W1 + t * (2 * DD);
    for (int j = 0; j < 2 * DD; ++j) x = fmaf(w1r[j], cat[j], x);
    x = (x > 0.f) ? x : 0.01f * x;

    float p0 = W2[t] * x;
    float p1 = W2[DD + t] * x;
    __shared__ float red[4];
    #pragma unroll
    for (int off = 32; off >= 1; off >>= 1) {
        p0 += __shfl_xor(p0, off);
        p1 += __shfl_xor(p1, off);
    }
    if ((t & 63) == 0) { red[t >> 6] = p0; red[2 + (t >> 6)] = p1; }
    __syncthreads();
    if (t == 0) {
        float l0 = red[0] + red[1] + b2[0];
        float l1 = red[2] + red[3] + b2[1];
        float mm = fmaxf(l0, l1);
        float e0 = expf(l0 - mm), e1 = expf(l1 - mm);
        float inv = 1.f / (e0 + e1);
        out[2 * b]     = e0 * inv;
        out[2 * b + 1] = e1 * inv;
    }
}

// ---------------------------------------------------------------------------
extern "C" void kernel_launch(void* const* d_in, const int* in_sizes, int n_in,
                              void* d_out, int out_size, void* d_ws, size_t ws_size,
                              hipStream_t stream) {
    const int*   batch     = (const int*)d_in[0];
    const int*   node_ids  = (const int*)d_in[1];
    const int*   neigh_ids = (const int*)d_in[2];
    const int*   ext_neigh = (const int*)d_in[3];
    const float* E         = (const float*)d_in[4];
    const float* W         = (const float*)d_in[5];
    const float* M         = (const float*)d_in[6];
    const float* U         = (const float*)d_in[7];
    const float* V         = (const float*)d_in[8];
    const float* W1        = (const float*)d_in[9];
    const float* b1        = (const float*)d_in[10];
    const float* W2        = (const float*)d_in[11];
    const float* b2        = (const float*)d_in[12];

    __half* WE = (__half*)d_ws;                     // 12.8 MB
    __half* ME = WE + (size_t)VINT * DD;            // 12.8 MB
    float*  H  = (float*)(ME + (size_t)VINT * DD);  // 5.12 MB
    float*  UH = H  + (size_t)NN * DD;              // 5.12 MB
    float*  VH = UH + (size_t)NN * DD;              // 5.12 MB
    float*  EA = VH + (size_t)NN * DD;              // 5.12 MB
    float*  out = (float*)d_out;

    k_gemm_dual<__half><<<(VINT + PROWS - 1) / PROWS, 128, 0, stream>>>(E, W, M, WE, ME, VINT);
    k_node<<<NN / 4, 128, 0, stream>>>(node_ids, neigh_ids, WE, ME, H);
    k_gemm_dual<float><<<(NN + PROWS - 1) / PROWS, 128, 0, stream>>>(H, U, V, UH, VH, NN);
    k_ext2<<<NN / 4, 128, 0, stream>>>(ext_neigh, UH, VH, EA);
    k_mlp<<<BB, 128, 0, stream>>>(batch, EA, W1, b1, W2, b2, out);
}

// Round 5
// 158.387 us; speedup vs baseline: 2.6661x; 1.2089x over previous
//
#include <hip/hip_runtime.h>
#include <hip/hip_fp16.h>

#define VINT 50000
#define NN   10000
#define KK   16
#define DINT 8
#define DEXT 16
#define DD   128
#define BB   2048

typedef __attribute__((ext_vector_type(8))) short  bf16x8;
typedef __attribute__((ext_vector_type(4))) short  short4v;
typedef __attribute__((ext_vector_type(4))) float  f32x4;

struct __align__(8) half4 { __half2 a, b; };

__device__ inline void store_acc(__half* p, f32x4 v) {
    half4 h;
    h.a = __floats2half2_rn(v[0], v[1]);
    h.b = __floats2half2_rn(v[2], v[3]);
    *(half4*)p = h;
}
__device__ inline void store_acc(float* p, f32x4 v) {
    *(float4*)p = make_float4(v[0], v[1], v[2], v[3]);
}

// ---------------------------------------------------------------------------
// Split fp32 -> bf16 hi + bf16 lo (RNE both).  x ~= hi + lo, residual ~2^-18.
// ---------------------------------------------------------------------------
__device__ inline void split_bf16(float f, short& h, short& l) {
    unsigned u  = __float_as_uint(f);
    unsigned hb = (u + 0x7FFFu + ((u >> 16) & 1u)) & 0xFFFF0000u;
    h = (short)(hb >> 16);
    float r = f - __uint_as_float(hb);
    unsigned u2 = __float_as_uint(r);
    l = (short)((u2 + 0x7FFFu + ((u2 >> 16) & 1u)) >> 16);
}

__global__ __launch_bounds__(256) void k_split(
    const float* __restrict__ src, short* __restrict__ hi,
    short* __restrict__ lo, int n4)
{
    int i = blockIdx.x * 256 + threadIdx.x;
    if (i >= n4) return;
    float4 v = ((const float4*)src)[i];
    float fv[4] = {v.x, v.y, v.z, v.w};
    short h[4], l[4];
    #pragma unroll
    for (int j = 0; j < 4; ++j) split_bf16(fv[j], h[j], l[j]);
    short4v hv = {h[0], h[1], h[2], h[3]};
    short4v lv = {l[0], l[1], l[2], l[3]};
    ((short4v*)hi)[i] = hv;
    ((short4v*)lo)[i] = lv;
}

// All four 128x128 weight mats in one launch: blocks [0..15]=W,[16..31]=M,
// [32..47]=U,[48..63]=V.  W/M stack into WMhi/lo rows 0-255; U/V into UVhi/lo.
__global__ __launch_bounds__(256) void k_split_mats(
    const float* __restrict__ W, const float* __restrict__ M,
    const float* __restrict__ U, const float* __restrict__ V,
    short* __restrict__ WMhi, short* __restrict__ WMlo,
    short* __restrict__ UVhi, short* __restrict__ UVlo)
{
    int which = blockIdx.x >> 4;
    int i = (blockIdx.x & 15) * 256 + threadIdx.x;   // float4 index, 0..4095
    const float* src = (which == 0) ? W : (which == 1) ? M : (which == 2) ? U : V;
    short* hi = (which < 2) ? WMhi : UVhi;
    short* lo = (which < 2) ? WMlo : UVlo;
    int off = (which & 1) * (DD * DD / 4);
    float4 v = ((const float4*)src)[i];
    float fv[4] = {v.x, v.y, v.z, v.w};
    short h[4], l[4];
    #pragma unroll
    for (int j = 0; j < 4; ++j) split_bf16(fv[j], h[j], l[j]);
    short4v hv = {h[0], h[1], h[2], h[3]};
    short4v lv = {l[0], l[1], l[2], l[3]};
    ((short4v*)hi)[off + i] = hv;
    ((short4v*)lo)[off + i] = lv;
}

// ---------------------------------------------------------------------------
// MFMA dual row-transform: OA[v] = A @ X[v], OB[v] = B @ X[v], split-bf16.
// D = AB(256x128) @ X^T(128xnrows).  Block: 256 thr (4 waves), 64 n-cols,
// all 256 m-rows (wave w owns m in [64w,64w+64)).  No LDS: A/B frags are
// contiguous 16B row-chunks (lane&15 = m/n, (lane>>4)*8 = k).  3 MFMA per
// tile: hi*hi + hi*lo + lo*hi (lo*lo ~2^-18, dropped).
// ---------------------------------------------------------------------------
template <typename OutT>
__global__ __launch_bounds__(256, 2) void k_mfma_dual(
    const short* __restrict__ Xhi, const short* __restrict__ Xlo,
    const short* __restrict__ ABhi, const short* __restrict__ ABlo,
    OutT* __restrict__ OA, OutT* __restrict__ OB, int nrows)
{
    const int n0 = blockIdx.x * 64;
    const int w  = threadIdx.x >> 6;
    const int l  = threadIdx.x & 63;
    const int lr = l & 15;
    const int lk = l >> 4;

    f32x4 acc[4][4];
    #pragma unroll
    for (int mi = 0; mi < 4; ++mi)
        #pragma unroll
        for (int ni = 0; ni < 4; ++ni)
            acc[mi][ni] = (f32x4){0.f, 0.f, 0.f, 0.f};

    const bf16x8 zf = {0, 0, 0, 0, 0, 0, 0, 0};

    for (int ks = 0; ks < 4; ++ks) {
        const int kb = ks * 32 + lk * 8;
        bf16x8 ah[4], al[4], bh[4], bl[4];
        #pragma unroll
        for (int mi = 0; mi < 4; ++mi) {
            int m = w * 64 + mi * 16 + lr;
            ah[mi] = *(const bf16x8*)&ABhi[m * DD + kb];
            al[mi] = *(const bf16x8*)&ABlo[m * DD + kb];
        }
        #pragma unroll
        for (int ni = 0; ni < 4; ++ni) {
            int n = n0 + ni * 16 + lr;
            if (n < nrows) {
                bh[ni] = *(const bf16x8*)&Xhi[(size_t)n * DD + kb];
                bl[ni] = *(const bf16x8*)&Xlo[(size_t)n * DD + kb];
            } else { bh[ni] = zf; bl[ni] = zf; }
        }
        #pragma unroll
        for (int mi = 0; mi < 4; ++mi)
            #pragma unroll
            for (int ni = 0; ni < 4; ++ni) {
                acc[mi][ni] = __builtin_amdgcn_mfma_f32_16x16x32_bf16(ah[mi], bh[ni], acc[mi][ni], 0, 0, 0);
                acc[mi][ni] = __builtin_amdgcn_mfma_f32_16x16x32_bf16(ah[mi], bl[ni], acc[mi][ni], 0, 0, 0);
                acc[mi][ni] = __builtin_amdgcn_mfma_f32_16x16x32_bf16(al[mi], bh[ni], acc[mi][ni], 0, 0, 0);
            }
    }

    // D[m][n]: lane holds rows m=tile+lk*4+r (r=0..3), col n=tile+lr.
    // Output row v=n, cols m..m+3 (contiguous): 4-elem store per tile.
    #pragma unroll
    for (int ni = 0; ni < 4; ++ni) {
        int n = n0 + ni * 16 + lr;
        if (n >= nrows) continue;
        #pragma unroll
        for (int mi = 0; mi < 4; ++mi) {
            int m = w * 64 + mi * 16 + lk * 4;
            if (m < DD) store_acc(&OA[(size_t)n * DD + m], acc[mi][ni]);
            else        store_acc(&OB[(size_t)n * DD + (m - DD)], acc[mi][ni]);
        }
    }
}

// ---------------------------------------------------------------------------
// Kernel 2: per node n: r[d] = sum_k relu(WE[nid]+sum_e ME[gid]); h = softmax(r)
// ---------------------------------------------------------------------------
__global__ __launch_bounds__(128) void k_node(
    const int* __restrict__ node_ids, const int* __restrict__ neigh_ids,
    const __half* __restrict__ WE, const __half* __restrict__ ME,
    float* __restrict__ H)
{
    __shared__ int idx[4][KK * (1 + DINT)];
    const int t  = threadIdx.x;
    const int n0 = blockIdx.x * 4;

    if (t < 4 * KK) idx[t >> 4][t & 15] = node_ids[n0 * KK + t];
    for (int x = t; x < 4 * KK * DINT; x += 128)
        idx[x >> 7][KK + (x & 127)] = neigh_ids[n0 * KK * DINT + x];
    __syncthreads();

    const int g = t >> 5, c = t & 31;
    const int n = n0 + g;
    const int* ids = idx[g];

    float rx = 0.f, ry = 0.f, rz = 0.f, rw = 0.f;
    #pragma unroll 4
    for (int k = 0; k < KK; ++k) {
        half4 wv = *(const half4*)(WE + (size_t)ids[k] * DD + 4 * c);
        float2 lo = __half22float2(wv.a), hi = __half22float2(wv.b);
        float sx = lo.x, sy = lo.y, sz = hi.x, sw = hi.y;
        #pragma unroll
        for (int e = 0; e < DINT; ++e) {
            half4 mv = *(const half4*)(ME + (size_t)ids[KK + k * DINT + e] * DD + 4 * c);
            float2 ml = __half22float2(mv.a), mh = __half22float2(mv.b);
            sx += ml.x; sy += ml.y; sz += mh.x; sw += mh.y;
        }
        rx += fmaxf(sx, 0.f); ry += fmaxf(sy, 0.f);
        rz += fmaxf(sz, 0.f); rw += fmaxf(sw, 0.f);
    }

    float mx = fmaxf(fmaxf(rx, ry), fmaxf(rz, rw));
    #pragma unroll
    for (int off = 16; off >= 1; off >>= 1) mx = fmaxf(mx, __shfl_xor(mx, off));
    float ex = expf(rx - mx), ey = expf(ry - mx), ez = expf(rz - mx), ew = expf(rw - mx);
    float s = ex + ey + ez + ew;
    #pragma unroll
    for (int off = 16; off >= 1; off >>= 1) s += __shfl_xor(s, off);
    float inv = 1.f / s;
    *(float4*)(H + (size_t)n * DD + 4 * c) = make_float4(ex * inv, ey * inv, ez * inv, ew * inv);
}

// ---------------------------------------------------------------------------
// Kernel 3: e_all[n] = softmax(relu(UH[n] + sum_j VH[ext[n,j]]))
// ---------------------------------------------------------------------------
__global__ __launch_bounds__(128) void k_ext2(
    const int* __restrict__ ext_neigh, const float* __restrict__ UH,
    const float* __restrict__ VH, float* __restrict__ EALL)
{
    __shared__ int idx[4][DEXT];
    const int t  = threadIdx.x;
    const int n0 = blockIdx.x * 4;
    if (t < 4 * DEXT) idx[t >> 4][t & 15] = ext_neigh[n0 * DEXT + t];
    __syncthreads();

    const int g = t >> 5, c = t & 31;
    const int n = n0 + g;
    float4 a = *(const float4*)(UH + (size_t)n * DD + 4 * c);
    float sx = a.x, sy = a.y, sz = a.z, sw = a.w;
    #pragma unroll
    for (int j = 0; j < DEXT; ++j) {
        float4 v = *(const float4*)(VH + (size_t)idx[g][j] * DD + 4 * c);
        sx += v.x; sy += v.y; sz += v.z; sw += v.w;
    }
    sx = fmaxf(sx, 0.f); sy = fmaxf(sy, 0.f);
    sz = fmaxf(sz, 0.f); sw = fmaxf(sw, 0.f);

    float mx = fmaxf(fmaxf(sx, sy), fmaxf(sz, sw));
    #pragma unroll
    for (int off = 16; off >= 1; off >>= 1) mx = fmaxf(mx, __shfl_xor(mx, off));
    float ex = expf(sx - mx), ey = expf(sy - mx), ez = expf(sz - mx), ew = expf(sw - mx);
    float s = ex + ey + ez + ew;
    #pragma unroll
    for (int off = 16; off >= 1; off >>= 1) s += __shfl_xor(s, off);
    float inv = 1.f / s;
    *(float4*)(EALL + (size_t)n * DD + 4 * c) = make_float4(ex * inv, ey * inv, ez * inv, ew * inv);
}

// ---------------------------------------------------------------------------
// Kernel 4: per batch pair: 2-layer MLP head + softmax(2)
// ---------------------------------------------------------------------------
__global__ __launch_bounds__(128) void k_mlp(
    const int* __restrict__ batch, const float* __restrict__ EALL,
    const float* __restrict__ W1, const float* __restrict__ b1,
    const float* __restrict__ W2, const float* __restrict__ b2,
    float* __restrict__ out)
{
    const int b = blockIdx.x;
    const int t = threadIdx.x;
    __shared__ float cat[2 * DD];
    const int ia = batch[2 * b];
    const int ib = batch[2 * b + 1];
    cat[t]      = EALL[(size_t)ia * DD + t];
    cat[DD + t] = EALL[(size_t)ib * DD + t];
    __syncthreads();

    float x = b1[t];
    const float* w1r = W1 + t * (2 * DD);
    for (int j = 0; j < 2 * DD; ++j) x = fmaf(w1r[j], cat[j], x);
    x = (x > 0.f) ? x : 0.01f * x;

    float p0 = W2[t] * x;
    float p1 = W2[DD + t] * x;
    __shared__ float red[4];
    #pragma unroll
    for (int off = 32; off >= 1; off >>= 1) {
        p0 += __shfl_xor(p0, off);
        p1 += __shfl_xor(p1, off);
    }
    if ((t & 63) == 0) { red[t >> 6] = p0; red[2 + (t >> 6)] = p1; }
    __syncthreads();
    if (t == 0) {
        float l0 = red[0] + red[1] + b2[0];
        float l1 = red[2] + red[3] + b2[1];
        float mm = fmaxf(l0, l1);
        float e0 = expf(l0 - mm), e1 = expf(l1 - mm);
        float inv = 1.f / (e0 + e1);
        out[2 * b]     = e0 * inv;
        out[2 * b + 1] = e1 * inv;
    }
}

// ---------------------------------------------------------------------------
extern "C" void kernel_launch(void* const* d_in, const int* in_sizes, int n_in,
                              void* d_out, int out_size, void* d_ws, size_t ws_size,
                              hipStream_t stream) {
    const int*   batch     = (const int*)d_in[0];
    const int*   node_ids  = (const int*)d_in[1];
    const int*   neigh_ids = (const int*)d_in[2];
    const int*   ext_neigh = (const int*)d_in[3];
    const float* E         = (const float*)d_in[4];
    const float* W         = (const float*)d_in[5];
    const float* M         = (const float*)d_in[6];
    const float* U         = (const float*)d_in[7];
    const float* V         = (const float*)d_in[8];
    const float* W1        = (const float*)d_in[9];
    const float* b1        = (const float*)d_in[10];
    const float* W2        = (const float*)d_in[11];
    const float* b2        = (const float*)d_in[12];

    // workspace layout (56.6 MB total; all 16B-aligned)
    __half* WE   = (__half*)d_ws;                    // 12.8 MB
    __half* ME   = WE + (size_t)VINT * DD;           // 12.8 MB
    float*  H    = (float*)(ME + (size_t)VINT * DD); // 5.12 MB
    short*  WMhi = (short*)(H + (size_t)NN * DD);    // 64 KB
    short*  WMlo = WMhi + 256 * DD;                  // 64 KB
    short*  UVhi = WMlo + 256 * DD;                  // 64 KB
    short*  UVlo = UVhi + 256 * DD;                  // 64 KB
    short*  Ehi  = UVlo + 256 * DD;                  // 12.8 MB
    short*  Elo  = Ehi + (size_t)VINT * DD;          // 12.8 MB
    // aliases into the Ehi/Elo region (dead after k_mfma_dual<half>):
    short*  Hhi  = Ehi;                              // 2.56 MB
    short*  Hlo  = Hhi + (size_t)NN * DD;            // 2.56 MB
    float*  UH   = (float*)(Hlo + (size_t)NN * DD);  // 5.12 MB
    float*  VH   = UH + (size_t)NN * DD;             // 5.12 MB
    float*  EA   = VH + (size_t)NN * DD;             // 5.12 MB
    float*  out  = (float*)d_out;

    k_split<<<(VINT * DD / 4 + 255) / 256, 256, 0, stream>>>(E, Ehi, Elo, VINT * DD / 4);
    k_split_mats<<<64, 256, 0, stream>>>(W, M, U, V, WMhi, WMlo, UVhi, UVlo);
    k_mfma_dual<__half><<<(VINT + 63) / 64, 256, 0, stream>>>(Ehi, Elo, WMhi, WMlo, WE, ME, VINT);
    k_node<<<NN / 4, 128, 0, stream>>>(node_ids, neigh_ids, WE, ME, H);
    k_split<<<(NN * DD / 4 + 255) / 256, 256, 0, stream>>>(H, Hhi, Hlo, NN * DD / 4);
    k_mfma_dual<float><<<(NN + 63) / 64, 256, 0, stream>>>(Hhi, Hlo, UVhi, UVlo, UH, VH, NN);
    k_ext2<<<NN / 4, 128, 0, stream>>>(ext_neigh, UH, VH, EA);
    k_mlp<<<BB, 128, 0, stream>>>(batch, EA, W1, b1, W2, b2, out);
}

// Round 6
// 125.057 us; speedup vs baseline: 3.3767x; 1.2665x over previous
//
#include <hip/hip_runtime.h>
#include <hip/hip_fp16.h>

#define VINT 50000
#define NN   10000
#define KK   16
#define DINT 8
#define DEXT 16
#define DD   128
#define BB   2048

typedef __attribute__((ext_vector_type(8))) short  bf16x8;
typedef __attribute__((ext_vector_type(4))) short  short4v;
typedef __attribute__((ext_vector_type(4))) float  f32x4;

struct __align__(8) half4 { __half2 a, b; };

__device__ inline short bf_rne(float f) {
    unsigned u = __float_as_uint(f);
    return (short)((u + 0x7FFFu + ((u >> 16) & 1u)) >> 16);
}

__device__ inline void store_acc(__half* p, f32x4 v) {
    half4 h;
    h.a = __floats2half2_rn(v[0], v[1]);
    h.b = __floats2half2_rn(v[2], v[3]);
    *(half4*)p = h;
}
__device__ inline void store_acc(float* p, f32x4 v) {
    *(float4*)p = make_float4(v[0], v[1], v[2], v[3]);
}

// ---------------------------------------------------------------------------
// fp32 -> bf16 (RNE) bulk convert, float4/thread.
// ---------------------------------------------------------------------------
__global__ __launch_bounds__(256) void k_convert(
    const float* __restrict__ src, short* __restrict__ dst, int n4)
{
    int i = blockIdx.x * 256 + threadIdx.x;
    if (i >= n4) return;
    float4 v = ((const float4*)src)[i];
    short4v o = {bf_rne(v.x), bf_rne(v.y), bf_rne(v.z), bf_rne(v.w)};
    ((short4v*)dst)[i] = o;
}

// Four 128x128 weight mats: blocks [0..15]=W,[16..31]=M,[32..47]=U,[48..63]=V.
// W/M stack into WMbf rows 0-255; U/V into UVbf rows 0-255.
__global__ __launch_bounds__(256) void k_convert_mats(
    const float* __restrict__ W, const float* __restrict__ M,
    const float* __restrict__ U, const float* __restrict__ V,
    short* __restrict__ WMbf, short* __restrict__ UVbf)
{
    int which = blockIdx.x >> 4;
    int i = (blockIdx.x & 15) * 256 + threadIdx.x;   // float4 index, 0..4095
    const float* src = (which == 0) ? W : (which == 1) ? M : (which == 2) ? U : V;
    short* dst = (which < 2) ? WMbf : UVbf;
    int off = (which & 1) * (DD * DD / 4);
    float4 v = ((const float4*)src)[i];
    short4v o = {bf_rne(v.x), bf_rne(v.y), bf_rne(v.z), bf_rne(v.w)};
    ((short4v*)dst)[off + i] = o;
}

// ---------------------------------------------------------------------------
// MFMA dual row-transform: OA[v] = A @ X[v], OB[v] = B @ X[v], bf16 inputs,
// fp32 accumulate. D = AB(256x128) @ X^T(128 x nrows). Block: 256 thr
// (4 waves), 64 n-cols; wave w owns m in [64w, 64w+64). No LDS.
// ---------------------------------------------------------------------------
template <typename OutT>
__global__ __launch_bounds__(256, 2) void k_mfma_dual(
    const short* __restrict__ Xbf, const short* __restrict__ ABbf,
    OutT* __restrict__ OA, OutT* __restrict__ OB, int nrows)
{
    const int n0 = blockIdx.x * 64;
    const int w  = threadIdx.x >> 6;
    const int l  = threadIdx.x & 63;
    const int lr = l & 15;
    const int lk = l >> 4;

    f32x4 acc[4][4];
    #pragma unroll
    for (int mi = 0; mi < 4; ++mi)
        #pragma unroll
        for (int ni = 0; ni < 4; ++ni)
            acc[mi][ni] = (f32x4){0.f, 0.f, 0.f, 0.f};

    const bf16x8 zf = {0, 0, 0, 0, 0, 0, 0, 0};

    for (int ks = 0; ks < 4; ++ks) {
        const int kb = ks * 32 + lk * 8;
        bf16x8 ah[4], bh[4];
        #pragma unroll
        for (int mi = 0; mi < 4; ++mi) {
            int m = w * 64 + mi * 16 + lr;
            ah[mi] = *(const bf16x8*)&ABbf[m * DD + kb];
        }
        #pragma unroll
        for (int ni = 0; ni < 4; ++ni) {
            int n = n0 + ni * 16 + lr;
            bh[ni] = (n < nrows) ? *(const bf16x8*)&Xbf[(size_t)n * DD + kb] : zf;
        }
        #pragma unroll
        for (int mi = 0; mi < 4; ++mi)
            #pragma unroll
            for (int ni = 0; ni < 4; ++ni)
                acc[mi][ni] = __builtin_amdgcn_mfma_f32_16x16x32_bf16(ah[mi], bh[ni], acc[mi][ni], 0, 0, 0);
    }

    // D[m][n]: lane holds col n=tile+lr, rows m=tile+lk*4+r (r=0..3).
    #pragma unroll
    for (int ni = 0; ni < 4; ++ni) {
        int n = n0 + ni * 16 + lr;
        if (n >= nrows) continue;
        #pragma unroll
        for (int mi = 0; mi < 4; ++mi) {
            int m = w * 64 + mi * 16 + lk * 4;
            if (m < DD) store_acc(&OA[(size_t)n * DD + m], acc[mi][ni]);
            else        store_acc(&OB[(size_t)n * DD + (m - DD)], acc[mi][ni]);
        }
    }
}

// ---------------------------------------------------------------------------
// Kernel 2: per node n: r[d] = sum_k relu(WE[nid]+sum_e ME[gid]); h=softmax(r).
// One node per wave-64: lanes 0-31 do k=0..7, lanes 32-63 do k=8..15
// (lane&31 owns cols 4c..4c+3); partials combined with __shfl_xor(.,32).
// Output H written directly as bf16 (feeds the UH/VH MFMA GEMM).
// ---------------------------------------------------------------------------
__global__ __launch_bounds__(256) void k_node(
    const int* __restrict__ node_ids, const int* __restrict__ neigh_ids,
    const __half* __restrict__ WE, const __half* __restrict__ ME,
    short* __restrict__ Hbf)
{
    __shared__ int idx[4][KK * (1 + DINT)];   // per node: [0..15]=nid, [16..143]=gid
    const int t  = threadIdx.x;
    const int n0 = blockIdx.x * 4;

    if (t < 4 * KK) idx[t >> 4][t & 15] = node_ids[n0 * KK + t];
    for (int x = t; x < 4 * KK * DINT; x += 256)
        idx[x >> 7][KK + (x & 127)] = neigh_ids[n0 * KK * DINT + x];
    __syncthreads();

    const int w  = t >> 6;          // node within block
    const int l  = t & 63;
    const int c  = l & 31;          // column quad owner
    const int hf = l >> 5;          // k-half
    const int n  = n0 + w;
    const int* ids = idx[w];

    float rx = 0.f, ry = 0.f, rz = 0.f, rw = 0.f;
    #pragma unroll
    for (int kk = 0; kk < 8; ++kk) {
        const int k = hf * 8 + kk;
        half4 wv = *(const half4*)(WE + (size_t)ids[k] * DD + 4 * c);
        float2 lo = __half22float2(wv.a), hi = __half22float2(wv.b);
        float sx = lo.x, sy = lo.y, sz = hi.x, sw = hi.y;
        #pragma unroll
        for (int e = 0; e < DINT; ++e) {
            half4 mv = *(const half4*)(ME + (size_t)ids[KK + k * DINT + e] * DD + 4 * c);
            float2 ml = __half22float2(mv.a), mh = __half22float2(mv.b);
            sx += ml.x; sy += ml.y; sz += mh.x; sw += mh.y;
        }
        rx += fmaxf(sx, 0.f); ry += fmaxf(sy, 0.f);
        rz += fmaxf(sz, 0.f); rw += fmaxf(sw, 0.f);
    }

    // combine k-halves across the 32-lane boundary
    rx += __shfl_xor(rx, 32); ry += __shfl_xor(ry, 32);
    rz += __shfl_xor(rz, 32); rw += __shfl_xor(rw, 32);

    // softmax over 128 cols (each 32-lane half holds identical data)
    float mx = fmaxf(fmaxf(rx, ry), fmaxf(rz, rw));
    #pragma unroll
    for (int off = 16; off >= 1; off >>= 1) mx = fmaxf(mx, __shfl_xor(mx, off));
    float ex = expf(rx - mx), ey = expf(ry - mx), ez = expf(rz - mx), ew = expf(rw - mx);
    float s = ex + ey + ez + ew;
    #pragma unroll
    for (int off = 16; off >= 1; off >>= 1) s += __shfl_xor(s, off);
    float inv = 1.f / s;
    if (hf == 0) {
        short4v o = {bf_rne(ex * inv), bf_rne(ey * inv), bf_rne(ez * inv), bf_rne(ew * inv)};
        *(short4v*)(Hbf + (size_t)n * DD + 4 * c) = o;
    }
}

// ---------------------------------------------------------------------------
// Kernel 3: e_all[n] = softmax(relu(UH[n] + sum_j VH[ext[n,j]])).
// One node per wave-64: half hf sums VH rows j=hf*8..hf*8+7 (+UH on hf==0);
// combine with __shfl_xor(.,32).
// ---------------------------------------------------------------------------
__global__ __launch_bounds__(256) void k_ext2(
    const int* __restrict__ ext_neigh, const float* __restrict__ UH,
    const float* __restrict__ VH, float* __restrict__ EALL)
{
    __shared__ int idx[4][DEXT];
    const int t  = threadIdx.x;
    const int n0 = blockIdx.x * 4;
    if (t < 4 * DEXT) idx[t >> 4][t & 15] = ext_neigh[n0 * DEXT + t];
    __syncthreads();

    const int w  = t >> 6;
    const int l  = t & 63;
    const int c  = l & 31;
    const int hf = l >> 5;
    const int n  = n0 + w;

    float sx = 0.f, sy = 0.f, sz = 0.f, sw = 0.f;
    if (hf == 0) {
        float4 a = *(const float4*)(UH + (size_t)n * DD + 4 * c);
        sx = a.x; sy = a.y; sz = a.z; sw = a.w;
    }
    #pragma unroll
    for (int jj = 0; jj < 8; ++jj) {
        float4 v = *(const float4*)(VH + (size_t)idx[w][hf * 8 + jj] * DD + 4 * c);
        sx += v.x; sy += v.y; sz += v.z; sw += v.w;
    }
    sx += __shfl_xor(sx, 32); sy += __shfl_xor(sy, 32);
    sz += __shfl_xor(sz, 32); sw += __shfl_xor(sw, 32);

    sx = fmaxf(sx, 0.f); sy = fmaxf(sy, 0.f);
    sz = fmaxf(sz, 0.f); sw = fmaxf(sw, 0.f);

    float mx = fmaxf(fmaxf(sx, sy), fmaxf(sz, sw));
    #pragma unroll
    for (int off = 16; off >= 1; off >>= 1) mx = fmaxf(mx, __shfl_xor(mx, off));
    float ex = expf(sx - mx), ey = expf(sy - mx), ez = expf(sz - mx), ew = expf(sw - mx);
    float s = ex + ey + ez + ew;
    #pragma unroll
    for (int off = 16; off >= 1; off >>= 1) s += __shfl_xor(s, off);
    float inv = 1.f / s;
    if (hf == 0)
        *(float4*)(EALL + (size_t)n * DD + 4 * c) = make_float4(ex * inv, ey * inv, ez * inv, ew * inv);
}

// ---------------------------------------------------------------------------
// Kernel 4: per batch pair: 2-layer MLP head + softmax(2)
// ---------------------------------------------------------------------------
__global__ __launch_bounds__(128) void k_mlp(
    const int* __restrict__ batch, const float* __restrict__ EALL,
    const float* __restrict__ W1, const float* __restrict__ b1,
    const float* __restrict__ W2, const float* __restrict__ b2,
    float* __restrict__ out)
{
    const int b = blockIdx.x;
    const int t = threadIdx.x;
    __shared__ float cat[2 * DD];
    const int ia = batch[2 * b];
    const int ib = batch[2 * b + 1];
    cat[t]      = EALL[(size_t)ia * DD + t];
    cat[DD + t] = EALL[(size_t)ib * DD + t];
    __syncthreads();

    float x = b1[t];
    const float* w1r = W1 + t * (2 * DD);
    for (int j = 0; j < 2 * DD; ++j) x = fmaf(w1r[j], cat[j], x);
    x = (x > 0.f) ? x : 0.01f * x;

    float p0 = W2[t] * x;
    float p1 = W2[DD + t] * x;
    __shared__ float red[4];
    #pragma unroll
    for (int off = 32; off >= 1; off >>= 1) {
        p0 += __shfl_xor(p0, off);
        p1 += __shfl_xor(p1, off);
    }
    if ((t & 63) == 0) { red[t >> 6] = p0; red[2 + (t >> 6)] = p1; }
    __syncthreads();
    if (t == 0) {
        float l0 = red[0] + red[1] + b2[0];
        float l1 = red[2] + red[3] + b2[1];
        float mm = fmaxf(l0, l1);
        float e0 = expf(l0 - mm), e1 = expf(l1 - mm);
        float inv = 1.f / (e0 + e1);
        out[2 * b]     = e0 * inv;
        out[2 * b + 1] = e1 * inv;
    }
}

// ---------------------------------------------------------------------------
extern "C" void kernel_launch(void* const* d_in, const int* in_sizes, int n_in,
                              void* d_out, int out_size, void* d_ws, size_t ws_size,
                              hipStream_t stream) {
    const int*   batch     = (const int*)d_in[0];
    const int*   node_ids  = (const int*)d_in[1];
    const int*   neigh_ids = (const int*)d_in[2];
    const int*   ext_neigh = (const int*)d_in[3];
    const float* E         = (const float*)d_in[4];
    const float* W         = (const float*)d_in[5];
    const float* M         = (const float*)d_in[6];
    const float* U         = (const float*)d_in[7];
    const float* V         = (const float*)d_in[8];
    const float* W1        = (const float*)d_in[9];
    const float* b1        = (const float*)d_in[10];
    const float* W2        = (const float*)d_in[11];
    const float* b2        = (const float*)d_in[12];

    // workspace layout (~56.4 MB, all 16B-aligned)
    __half* WE   = (__half*)d_ws;                    // 12.8 MB
    __half* ME   = WE + (size_t)VINT * DD;           // 12.8 MB
    short*  Ebf  = (short*)(ME + (size_t)VINT * DD); // 12.8 MB
    short*  Hbf  = Ebf + (size_t)VINT * DD;          // 2.56 MB
    short*  WMbf = Hbf + (size_t)NN * DD;            // 64 KB
    short*  UVbf = WMbf + 256 * DD;                  // 64 KB
    float*  UH   = (float*)(UVbf + 256 * DD);        // 5.12 MB
    float*  VH   = UH + (size_t)NN * DD;             // 5.12 MB
    float*  EA   = VH + (size_t)NN * DD;             // 5.12 MB
    float*  out  = (float*)d_out;

    k_convert<<<(VINT * DD / 4 + 255) / 256, 256, 0, stream>>>(E, Ebf, VINT * DD / 4);
    k_convert_mats<<<64, 256, 0, stream>>>(W, M, U, V, WMbf, UVbf);
    k_mfma_dual<__half><<<(VINT + 63) / 64, 256, 0, stream>>>(Ebf, WMbf, WE, ME, VINT);
    k_node<<<NN / 4, 256, 0, stream>>>(node_ids, neigh_ids, WE, ME, Hbf);
    k_mfma_dual<float><<<(NN + 63) / 64, 256, 0, stream>>>(Hbf, UVbf, UH, VH, NN);
    k_ext2<<<NN / 4, 256, 0, stream>>>(ext_neigh, UH, VH, EA);
    k_mlp<<<BB, 128, 0, stream>>>(batch, EA, W1, b1, W2, b2, out);
}